// Round 5
// baseline (372.437 us; speedup 1.0000x reference)
//
#include <hip/hip_runtime.h>

// MaskedSelfAttention: B=4, S=4096, D=1024, H=128. fp32 in/out, bf16 MFMA compute.
// ws (13.4 MiB): Qb bf16[16384][128] | Kb | Vt bf16[4][128][4096] | Wb bf16[384][1024]

typedef __bf16 bf16x8 __attribute__((ext_vector_type(8)));
typedef __bf16 bf16x4 __attribute__((ext_vector_type(4)));
typedef float  f32x4  __attribute__((ext_vector_type(4)));

#define MFMA16(a, b, c) __builtin_amdgcn_mfma_f32_16x16x32_bf16(a, b, c, 0, 0, 0)

// ---------------------------------------------------------------- prep_w ----
__global__ __launch_bounds__(256) void prep_w(
    const float* __restrict__ Wq, const float* __restrict__ Wk,
    const float* __restrict__ Wv, __bf16* __restrict__ Wb)
{
    int i = (blockIdx.x * 256 + threadIdx.x) * 4;      // 0..393215, step 4
    int row = i >> 10;
    const float* W = (row < 128) ? Wq : (row < 256) ? Wk : Wv;
    float4 v = *(const float4*)&W[(size_t)(row & 127) * 1024 + (i & 1023)];
    bf16x4 pk = {(__bf16)v.x, (__bf16)v.y, (__bf16)v.z, (__bf16)v.w};
    *(bf16x4*)&Wb[i] = pk;
}

// -------------------------------------------------------------- qkv_gemm ----
// C = x[16384,1024] @ W^T. Block tile 64x128 (grid (256,3) = 768 blocks =
// exactly 3 blocks/CU, 3 waves/SIMD). 4 waves 2x2, wave 32x64 (2x4 MFMA).
// BK=64. A: fp32 x converted during staging; B: bf16 Wb uint4 copy.
// Q/K row-major [s][h]; V transposed [b][h][s].
__global__ __launch_bounds__(256) void qkv_gemm(
    const float* __restrict__ x, const __bf16* __restrict__ Wb,
    const float* __restrict__ bq, const float* __restrict__ bk,
    const float* __restrict__ bv,
    __bf16* __restrict__ Qb, __bf16* __restrict__ Kb, __bf16* __restrict__ Vt)
{
    __shared__ __bf16 As[64][72];
    __shared__ __bf16 Bs[128][72];

    const int tid   = threadIdx.x;
    const int m0    = blockIdx.x * 64;
    const int which = blockIdx.y;           // 0=Q 1=K 2=V
    const int n0    = which * 128;          // Wb row base
    const int lane = tid & 63, wid = tid >> 6;
    const int quad = lane >> 4, l16 = lane & 15;
    const int wm = (wid >> 1) * 32, wn = (wid & 1) * 64;

    const f32x4 fzero = {0.f, 0.f, 0.f, 0.f};
    f32x4 acc[2][4];
#pragma unroll
    for (int i = 0; i < 2; ++i)
#pragma unroll
        for (int j = 0; j < 4; ++j) acc[i][j] = fzero;

    const int arow = tid >> 2, acol = (tid & 3) * 16;   // A: 64 rows, 16 elem/thr
    const int brow = tid >> 1, bcol = (tid & 1) * 32;   // B: 128 rows, 32 elem/thr

    for (int kk = 0; kk < 1024; kk += 64) {
        {   // A: 64x64 fp32 -> bf16
            const float* src = &x[(size_t)(m0 + arow) * 1024 + kk + acol];
            float4 a0 = *(const float4*)&src[0];
            float4 a1 = *(const float4*)&src[4];
            float4 a2 = *(const float4*)&src[8];
            float4 a3 = *(const float4*)&src[12];
            bf16x8 p0 = {(__bf16)a0.x, (__bf16)a0.y, (__bf16)a0.z, (__bf16)a0.w,
                         (__bf16)a1.x, (__bf16)a1.y, (__bf16)a1.z, (__bf16)a1.w};
            bf16x8 p1 = {(__bf16)a2.x, (__bf16)a2.y, (__bf16)a2.z, (__bf16)a2.w,
                         (__bf16)a3.x, (__bf16)a3.y, (__bf16)a3.z, (__bf16)a3.w};
            *(bf16x8*)&As[arow][acol]     = p0;
            *(bf16x8*)&As[arow][acol + 8] = p1;
        }
        {   // B: 128x64 bf16 copy
            const __bf16* src = &Wb[(size_t)(n0 + brow) * 1024 + kk + bcol];
#pragma unroll
            for (int q = 0; q < 4; ++q)
                *(uint4*)&Bs[brow][bcol + q * 8] = *(const uint4*)&src[q * 8];
        }
        __syncthreads();
#pragma unroll
        for (int ks = 0; ks < 2; ++ks) {
            const int k0 = ks * 32 + quad * 8;
            bf16x8 a[2], bb[4];
#pragma unroll
            for (int mt = 0; mt < 2; ++mt)
                a[mt] = *(const bf16x8*)&As[wm + mt * 16 + l16][k0];
#pragma unroll
            for (int nt = 0; nt < 4; ++nt)
                bb[nt] = *(const bf16x8*)&Bs[wn + nt * 16 + l16][k0];
#pragma unroll
            for (int mt = 0; mt < 2; ++mt)
#pragma unroll
                for (int nt = 0; nt < 4; ++nt)
                    acc[mt][nt] = MFMA16(a[mt], bb[nt], acc[mt][nt]);
        }
        __syncthreads();
    }

    const float* bias = (which == 0) ? bq : (which == 1) ? bk : bv;
    if (which < 2) {
        __bf16* dst = (which == 0) ? Qb : Kb;
#pragma unroll
        for (int nt = 0; nt < 4; ++nt) {
            int col = wn + nt * 16 + l16;
            float bvv = bias[col];
#pragma unroll
            for (int mt = 0; mt < 2; ++mt)
#pragma unroll
                for (int r = 0; r < 4; ++r) {
                    int row = m0 + wm + mt * 16 + quad * 4 + r; // D: row=quad*4+reg
                    dst[(size_t)row * 128 + col] = (__bf16)(acc[mt][nt][r] + bvv);
                }
        }
    } else {
#pragma unroll
        for (int nt = 0; nt < 4; ++nt) {
            int col = wn + nt * 16 + l16;               // head index
            float bvv = bias[col];
#pragma unroll
            for (int mt = 0; mt < 2; ++mt) {
                int row = m0 + wm + mt * 16 + quad * 4; // global seq of reg 0
                int bb_ = row >> 12, s = row & 4095;
                bf16x4 pk = {(__bf16)(acc[mt][nt][0] + bvv),
                             (__bf16)(acc[mt][nt][1] + bvv),
                             (__bf16)(acc[mt][nt][2] + bvv),
                             (__bf16)(acc[mt][nt][3] + bvv)};
                *(bf16x4*)&Vt[((size_t)(bb_ * 128 + col)) * 4096 + s] = pk;
            }
        }
    }
}

// -------------------------------------------------------------- flash_attn --
// v5: canonical flash blocking. Block = 64 q-rows, 4 waves (16 rows each).
// K/V tile staged in LDS ONCE per block (prefetch-to-regs, 32 VGPRs payload,
// double-barrier) and shared by all 4 waves -> 4x less global traffic than v4.
// Grid (64,4) = 256 blocks, longest-first. No cross-wave merge needed.
__global__ __launch_bounds__(256, 2) void flash_attn(
    const __bf16* __restrict__ Qb, const __bf16* __restrict__ Kb,
    const __bf16* __restrict__ Vt, const int* __restrict__ mask,
    float* __restrict__ out)
{
    __shared__ __bf16 Ks[64][136];    // [key][d]   17.4 KB (stride 68 dw: 2-way free)
    __shared__ __bf16 Vs[128][72];    // [head][key] 18.4 KB (stride 36 dw)
    __shared__ __bf16 pl[4][16][72];  // P transpose, per-wave                9.2 KB

    const int b    = blockIdx.y;
    const int tile = 63 - blockIdx.x;                  // longest work first
    const int r0   = tile * 64;
    const int nk   = tile + 1;                         // # of 64-key tiles
    const int tid = threadIdx.x, wid = tid >> 6, lane = tid & 63;
    const int quad = lane >> 4, l16 = lane & 15;
    const int wr0 = r0 + wid * 16;                     // wave's q-row base
    const int rowbase = wr0 + quad * 4;                // C-layout row of reg 0
    const size_t sb = (size_t)b * 4096;
    const float scale = 0.08838834764831845f;          // 1/sqrt(128)

    // staging thread map
    const int txk = tid >> 4, tck = (tid & 15) * 8;    // K: 16 rows/pass
    const int txv = tid >> 3, tcv = (tid & 7) * 8;     // V: 32 rows/pass

    bf16x8 qf[4];                                      // Q A-frags, scale folded
#pragma unroll
    for (int h = 0; h < 4; ++h) {
        qf[h] = *(const bf16x8*)&Qb[(sb + wr0 + l16) * 128 + h * 32 + quad * 8];
#pragma unroll
        for (int j = 0; j < 8; ++j) qf[h][j] = (__bf16)((float)qf[h][j] * scale);
    }

    float mi[4] = {-1e30f, -1e30f, -1e30f, -1e30f};
    float li[4] = {0.f, 0.f, 0.f, 0.f};
    const f32x4 fzero = {0.f, 0.f, 0.f, 0.f};
    f32x4 o[8];
#pragma unroll
    for (int hn = 0; hn < 8; ++hn) o[hn] = fzero;

    uint4 kreg[4], vreg[4];
    {   // preload tile 0
#pragma unroll
        for (int p = 0; p < 4; ++p)
            kreg[p] = *(const uint4*)&Kb[(sb + 0 + p * 16 + txk) * 128 + tck];
#pragma unroll
        for (int p = 0; p < 4; ++p)
            vreg[p] = *(const uint4*)&Vt[(size_t)(b * 128 + p * 32 + txv) * 4096 + 0 + tcv];
    }

    for (int t = 0; t < nk; ++t) {
        const int k0 = t * 64;
        __syncthreads();                               // prev compute done
#pragma unroll
        for (int p = 0; p < 4; ++p) *(uint4*)&Ks[p * 16 + txk][tck] = kreg[p];
#pragma unroll
        for (int p = 0; p < 4; ++p) *(uint4*)&Vs[p * 32 + txv][tcv] = vreg[p];
        __syncthreads();                               // tile staged
        if (t + 1 < nk) {                              // prefetch t+1 (in flight)
            const int kn = k0 + 64;
#pragma unroll
            for (int p = 0; p < 4; ++p)
                kreg[p] = *(const uint4*)&Kb[(sb + kn + p * 16 + txk) * 128 + tck];
#pragma unroll
            for (int p = 0; p < 4; ++p)
                vreg[p] = *(const uint4*)&Vt[(size_t)(b * 128 + p * 32 + txv) * 4096 + kn + tcv];
        }
        int mv = mask[sb + k0 + lane];
        // ---- S = Q K^T (16x64 per wave, frags from LDS) ----
        f32x4 s[4];
#pragma unroll
        for (int nt = 0; nt < 4; ++nt) s[nt] = fzero;
#pragma unroll
        for (int h = 0; h < 4; ++h)
#pragma unroll
            for (int nt = 0; nt < 4; ++nt) {
                bf16x8 kf = *(const bf16x8*)&Ks[nt * 16 + l16][h * 32 + quad * 8];
                s[nt] = MFMA16(qf[h], kf, s[nt]);
            }
        // ---- masking (wave-uniform fast path on interior unmasked tiles) ----
        unsigned long long mb = __ballot(mv != 0);
        if (mb != ~0ull || k0 + 63 > wr0) {
#pragma unroll
            for (int nt = 0; nt < 4; ++nt) {
                int kb_ = nt * 16 + l16;
                bool mok = (mb >> kb_) & 1;
                int kc = k0 + kb_;
#pragma unroll
                for (int r = 0; r < 4; ++r) {
                    bool ok = mok && (kc <= rowbase + r);
                    s[nt][r] = ok ? s[nt][r] : -1e30f;
                }
            }
        }
        // ---- online softmax per owned row ----
#pragma unroll
        for (int r = 0; r < 4; ++r) {
            float mx = fmaxf(fmaxf(s[0][r], s[1][r]), fmaxf(s[2][r], s[3][r]));
#pragma unroll
            for (int off = 1; off < 16; off <<= 1) mx = fmaxf(mx, __shfl_xor(mx, off));
            float mnew  = fmaxf(mi[r], mx);
            float alpha = __expf(mi[r] - mnew);
            float rs = 0.f;
#pragma unroll
            for (int nt = 0; nt < 4; ++nt) {
                float p = (s[nt][r] < -5e29f) ? 0.f : __expf(s[nt][r] - mnew);
                s[nt][r] = p;
                rs += p;
            }
#pragma unroll
            for (int off = 1; off < 16; off <<= 1) rs += __shfl_xor(rs, off);
            li[r] = li[r] * alpha + rs;
            mi[r] = mnew;
#pragma unroll
            for (int hn = 0; hn < 8; ++hn) o[hn][r] *= alpha;
        }
        // ---- P: C-layout -> A-layout via per-wave LDS (in-order DS) ----
#pragma unroll
        for (int nt = 0; nt < 4; ++nt)
#pragma unroll
            for (int r = 0; r < 4; ++r)
                pl[wid][quad * 4 + r][nt * 16 + l16] = (__bf16)s[nt][r];
        asm volatile("s_waitcnt lgkmcnt(0)" ::: "memory");
        // ---- O += P V (V frags from LDS) ----
#pragma unroll
        for (int ks = 0; ks < 2; ++ks) {
            bf16x8 ap = *(const bf16x8*)&pl[wid][l16][ks * 32 + quad * 8];
#pragma unroll
            for (int hn = 0; hn < 8; ++hn) {
                bf16x8 vf = *(const bf16x8*)&Vs[hn * 16 + l16][ks * 32 + quad * 8];
                o[hn] = MFMA16(ap, vf, o[hn]);
            }
        }
    }

    // ---- epilogue: normalize, fp32 store (wave owns its rows) ----
#pragma unroll
    for (int r = 0; r < 4; ++r) {
        float inv = 1.0f / li[r];
#pragma unroll
        for (int hn = 0; hn < 8; ++hn)
            out[(sb + rowbase + r) * 128 + hn * 16 + l16] = o[hn][r] * inv;
    }
}

// ----------------------------------------------------------------- launch ---
extern "C" void kernel_launch(void* const* d_in, const int* in_sizes, int n_in,
                              void* d_out, int out_size, void* d_ws, size_t ws_size,
                              hipStream_t stream)
{
    const float* x    = (const float*)d_in[0];
    const int*   mask = (const int*)d_in[1];
    const float* Wq   = (const float*)d_in[2];
    const float* bq   = (const float*)d_in[3];
    const float* Wk   = (const float*)d_in[4];
    const float* bk   = (const float*)d_in[5];
    const float* Wv   = (const float*)d_in[6];
    const float* bv   = (const float*)d_in[7];
    float* out = (float*)d_out;

    char* ws = (char*)d_ws;
    __bf16* Qb = (__bf16*)ws;                       // 4 MiB
    __bf16* Kb = Qb + (size_t)16384 * 128;          // 4 MiB
    __bf16* Vt = Kb + (size_t)16384 * 128;          // 4 MiB ([b][h][s])
    __bf16* Wb = Vt + (size_t)16384 * 128;          // 768 KiB

    prep_w<<<384, 256, 0, stream>>>(Wq, Wk, Wv, Wb);
    qkv_gemm<<<dim3(256, 3), 256, 0, stream>>>(x, Wb, bq, bk, bv, Qb, Kb, Vt);
    flash_attn<<<dim3(64, 4), 256, 0, stream>>>(Qb, Kb, Vt, mask, out);
}

// Round 6
// 334.496 us; speedup vs baseline: 1.1134x; 1.1134x over previous
//
#include <hip/hip_runtime.h>

// MaskedSelfAttention: B=4, S=4096, D=1024, H=128. fp32 in/out, bf16 MFMA compute.
// ws (13.6 MiB): Qb bf16[16384][128] | Kb | Vt bf16[4][128][4096] | Wb bf16[384][1024]
//              | ml float[4][64][2][64][2]

typedef __bf16 bf16x8 __attribute__((ext_vector_type(8)));
typedef __bf16 bf16x4 __attribute__((ext_vector_type(4)));
typedef float  f32x4  __attribute__((ext_vector_type(4)));

#define MFMA16(a, b, c) __builtin_amdgcn_mfma_f32_16x16x32_bf16(a, b, c, 0, 0, 0)

// ---------------------------------------------------------------- prep_w ----
__global__ __launch_bounds__(256) void prep_w(
    const float* __restrict__ Wq, const float* __restrict__ Wk,
    const float* __restrict__ Wv, __bf16* __restrict__ Wb)
{
    int i = (blockIdx.x * 256 + threadIdx.x) * 4;      // 0..393215, step 4
    int row = i >> 10;
    const float* W = (row < 128) ? Wq : (row < 256) ? Wk : Wv;
    float4 v = *(const float4*)&W[(size_t)(row & 127) * 1024 + (i & 1023)];
    bf16x4 pk = {(__bf16)v.x, (__bf16)v.y, (__bf16)v.z, (__bf16)v.w};
    *(bf16x4*)&Wb[i] = pk;
}

// -------------------------------------------------------------- qkv_gemm ----
// C = x[16384,1024] @ W^T. Block tile 64x128, grid (256,3) = 768 blocks =
// 3 blocks/CU. 4 waves 2x2, wave 32x64 (2x4 MFMA). BK=64. v6: register
// prefetch of next K-tile (32 VGPR payload) so staging latency overlaps MFMA.
__global__ __launch_bounds__(256, 3) void qkv_gemm(
    const float* __restrict__ x, const __bf16* __restrict__ Wb,
    const float* __restrict__ bq, const float* __restrict__ bk,
    const float* __restrict__ bv,
    __bf16* __restrict__ Qb, __bf16* __restrict__ Kb, __bf16* __restrict__ Vt)
{
    __shared__ __bf16 As[64][72];
    __shared__ __bf16 Bs[128][72];

    const int tid   = threadIdx.x;
    const int m0    = blockIdx.x * 64;
    const int which = blockIdx.y;           // 0=Q 1=K 2=V
    const int n0    = which * 128;          // Wb row base
    const int lane = tid & 63, wid = tid >> 6;
    const int quad = lane >> 4, l16 = lane & 15;
    const int wm = (wid >> 1) * 32, wn = (wid & 1) * 64;

    const f32x4 fzero = {0.f, 0.f, 0.f, 0.f};
    f32x4 acc[2][4];
#pragma unroll
    for (int i = 0; i < 2; ++i)
#pragma unroll
        for (int j = 0; j < 4; ++j) acc[i][j] = fzero;

    const int arow = tid >> 2, acol = (tid & 3) * 16;   // A: 64 rows, 16 el/thr
    const int brow = tid >> 1, bcol = (tid & 1) * 32;   // B: 128 rows, 32 el/thr

    float4 areg[4];
    uint4  breg[4];
    {   // preload kk = 0
        const float* srcA = &x[(size_t)(m0 + arow) * 1024 + acol];
#pragma unroll
        for (int q = 0; q < 4; ++q) areg[q] = *(const float4*)&srcA[q * 4];
        const __bf16* srcB = &Wb[(size_t)(n0 + brow) * 1024 + bcol];
#pragma unroll
        for (int q = 0; q < 4; ++q) breg[q] = *(const uint4*)&srcB[q * 8];
    }

    for (int kk = 0; kk < 1024; kk += 64) {
        __syncthreads();                    // prev compute done
        {   // store staged regs to LDS (fp32 -> bf16 for A)
            bf16x8 p0 = {(__bf16)areg[0].x, (__bf16)areg[0].y, (__bf16)areg[0].z, (__bf16)areg[0].w,
                         (__bf16)areg[1].x, (__bf16)areg[1].y, (__bf16)areg[1].z, (__bf16)areg[1].w};
            bf16x8 p1 = {(__bf16)areg[2].x, (__bf16)areg[2].y, (__bf16)areg[2].z, (__bf16)areg[2].w,
                         (__bf16)areg[3].x, (__bf16)areg[3].y, (__bf16)areg[3].z, (__bf16)areg[3].w};
            *(bf16x8*)&As[arow][acol]     = p0;
            *(bf16x8*)&As[arow][acol + 8] = p1;
#pragma unroll
            for (int q = 0; q < 4; ++q)
                *(uint4*)&Bs[brow][bcol + q * 8] = breg[q];
        }
        __syncthreads();                    // tile staged
        if (kk + 64 < 1024) {               // prefetch next (in flight over MFMA)
            const float* srcA = &x[(size_t)(m0 + arow) * 1024 + kk + 64 + acol];
#pragma unroll
            for (int q = 0; q < 4; ++q) areg[q] = *(const float4*)&srcA[q * 4];
            const __bf16* srcB = &Wb[(size_t)(n0 + brow) * 1024 + kk + 64 + bcol];
#pragma unroll
            for (int q = 0; q < 4; ++q) breg[q] = *(const uint4*)&srcB[q * 8];
        }
#pragma unroll
        for (int ks = 0; ks < 2; ++ks) {
            const int k0 = ks * 32 + quad * 8;
            bf16x8 a[2], bb[4];
#pragma unroll
            for (int mt = 0; mt < 2; ++mt)
                a[mt] = *(const bf16x8*)&As[wm + mt * 16 + l16][k0];
#pragma unroll
            for (int nt = 0; nt < 4; ++nt)
                bb[nt] = *(const bf16x8*)&Bs[wn + nt * 16 + l16][k0];
#pragma unroll
            for (int mt = 0; mt < 2; ++mt)
#pragma unroll
                for (int nt = 0; nt < 4; ++nt)
                    acc[mt][nt] = MFMA16(a[mt], bb[nt], acc[mt][nt]);
        }
    }

    const float* bias = (which == 0) ? bq : (which == 1) ? bk : bv;
    if (which < 2) {
        __bf16* dst = (which == 0) ? Qb : Kb;
#pragma unroll
        for (int nt = 0; nt < 4; ++nt) {
            int col = wn + nt * 16 + l16;
            float bvv = bias[col];
#pragma unroll
            for (int mt = 0; mt < 2; ++mt)
#pragma unroll
                for (int r = 0; r < 4; ++r) {
                    int row = m0 + wm + mt * 16 + quad * 4 + r; // D: row=quad*4+reg
                    dst[(size_t)row * 128 + col] = (__bf16)(acc[mt][nt][r] + bvv);
                }
        }
    } else {
#pragma unroll
        for (int nt = 0; nt < 4; ++nt) {
            int col = wn + nt * 16 + l16;               // head index
            float bvv = bias[col];
#pragma unroll
            for (int mt = 0; mt < 2; ++mt) {
                int row = m0 + wm + mt * 16 + quad * 4; // global seq of reg 0
                int bb_ = row >> 12, s = row & 4095;
                bf16x4 pk = {(__bf16)(acc[mt][nt][0] + bvv),
                             (__bf16)(acc[mt][nt][1] + bvv),
                             (__bf16)(acc[mt][nt][2] + bvv),
                             (__bf16)(acc[mt][nt][3] + bvv)};
                *(bf16x4*)&Vt[((size_t)(bb_ * 128 + col)) * 4096 + s] = pk;
            }
        }
    }
}

// -------------------------------------------------------------- flash_attn --
// v6: v5's LDS-shared 64-row block, but each (b,tile) is processed by TWO
// blocks splitting the key range (<=32 iters each) -> 512 balanced blocks =
// 2 blocks/CU. Each half writes pre-normalized bf16 partial O into the out
// buffer (half h -> bytes [h*16KB, (h+1)*16KB) of the tile's 32KB out region)
// + (m,l) to ws; merge_halves combines. Flattened grid, longest-first.
__global__ __launch_bounds__(256, 2) void flash_attn(
    const __bf16* __restrict__ Qb, const __bf16* __restrict__ Kb,
    const __bf16* __restrict__ Vt, const int* __restrict__ mask,
    float* __restrict__ out, float* __restrict__ ml)
{
    __shared__ __bf16 Ks[64][136];    // [key][d]
    __shared__ __bf16 Vs[128][72];    // [head][key]
    __shared__ __bf16 pl[4][16][72];  // P transpose, per-wave

    const int idx  = blockIdx.x;                       // 0..511
    const int tile = 63 - (idx >> 3);                  // longest first
    const int b    = (idx >> 1) & 3;
    const int half = idx & 1;
    const int r0   = tile * 64;
    const int nk   = tile + 1;
    const int nh   = (nk + 1) >> 1;
    const int t0   = half ? nh : 0;
    const int t1   = half ? nk : nh;

    const int tid = threadIdx.x, wid = tid >> 6, lane = tid & 63;
    const int quad = lane >> 4, l16 = lane & 15;
    const int wr0 = r0 + wid * 16;                     // wave's q-row base
    const size_t sb = (size_t)b * 4096;
    const float scale = 0.08838834764831845f;          // 1/sqrt(128)

    const int txk = tid >> 4, tck = (tid & 15) * 8;    // K staging map
    const int txv = tid >> 3, tcv = (tid & 7) * 8;     // V staging map

    bf16x8 qf[4];                                      // Q A-frags, scale folded
#pragma unroll
    for (int h = 0; h < 4; ++h) {
        qf[h] = *(const bf16x8*)&Qb[(sb + wr0 + l16) * 128 + h * 32 + quad * 8];
#pragma unroll
        for (int j = 0; j < 8; ++j) qf[h][j] = (__bf16)((float)qf[h][j] * scale);
    }

    float mi[4] = {-1e30f, -1e30f, -1e30f, -1e30f};
    float li[4] = {0.f, 0.f, 0.f, 0.f};
    const f32x4 fzero = {0.f, 0.f, 0.f, 0.f};
    f32x4 o[8];
#pragma unroll
    for (int hn = 0; hn < 8; ++hn) o[hn] = fzero;

    uint4 kreg[4], vreg[4];
    if (t0 < t1) {                                     // preload tile t0
        const int k0 = t0 * 64;
#pragma unroll
        for (int p = 0; p < 4; ++p)
            kreg[p] = *(const uint4*)&Kb[(sb + k0 + p * 16 + txk) * 128 + tck];
#pragma unroll
        for (int p = 0; p < 4; ++p)
            vreg[p] = *(const uint4*)&Vt[(size_t)(b * 128 + p * 32 + txv) * 4096 + k0 + tcv];
    }

    for (int t = t0; t < t1; ++t) {
        const int k0 = t * 64;
        __syncthreads();                               // prev compute done
#pragma unroll
        for (int p = 0; p < 4; ++p) *(uint4*)&Ks[p * 16 + txk][tck] = kreg[p];
#pragma unroll
        for (int p = 0; p < 4; ++p) *(uint4*)&Vs[p * 32 + txv][tcv] = vreg[p];
        __syncthreads();                               // tile staged
        if (t + 1 < t1) {                              // prefetch t+1
            const int kn = k0 + 64;
#pragma unroll
            for (int p = 0; p < 4; ++p)
                kreg[p] = *(const uint4*)&Kb[(sb + kn + p * 16 + txk) * 128 + tck];
#pragma unroll
            for (int p = 0; p < 4; ++p)
                vreg[p] = *(const uint4*)&Vt[(size_t)(b * 128 + p * 32 + txv) * 4096 + kn + tcv];
        }
        int mv = mask[sb + k0 + lane];
        // ---- S = Q K^T (16x64 per wave, K frags from LDS) ----
        f32x4 s[4];
#pragma unroll
        for (int nt = 0; nt < 4; ++nt) s[nt] = fzero;
#pragma unroll
        for (int h = 0; h < 4; ++h)
#pragma unroll
            for (int nt = 0; nt < 4; ++nt) {
                bf16x8 kf = *(const bf16x8*)&Ks[nt * 16 + l16][h * 32 + quad * 8];
                s[nt] = MFMA16(qf[h], kf, s[nt]);
            }
        // ---- masking (fast path: interior unmasked tiles skip) ----
        unsigned long long mb = __ballot(mv != 0);
        if (mb != ~0ull || k0 + 63 > wr0) {
            const int rowbase = wr0 + quad * 4;
#pragma unroll
            for (int nt = 0; nt < 4; ++nt) {
                int kb_ = nt * 16 + l16;
                bool mok = (mb >> kb_) & 1;
                int kc = k0 + kb_;
#pragma unroll
                for (int r = 0; r < 4; ++r) {
                    bool ok = mok && (kc <= rowbase + r);
                    s[nt][r] = ok ? s[nt][r] : -1e30f;
                }
            }
        }
        // ---- online softmax per owned row ----
#pragma unroll
        for (int r = 0; r < 4; ++r) {
            float mx = fmaxf(fmaxf(s[0][r], s[1][r]), fmaxf(s[2][r], s[3][r]));
#pragma unroll
            for (int off = 1; off < 16; off <<= 1) mx = fmaxf(mx, __shfl_xor(mx, off));
            float mnew  = fmaxf(mi[r], mx);
            float alpha = __expf(mi[r] - mnew);
            float rs = 0.f;
#pragma unroll
            for (int nt = 0; nt < 4; ++nt) {
                float p = (s[nt][r] < -5e29f) ? 0.f : __expf(s[nt][r] - mnew);
                s[nt][r] = p;
                rs += p;
            }
#pragma unroll
            for (int off = 1; off < 16; off <<= 1) rs += __shfl_xor(rs, off);
            li[r] = li[r] * alpha + rs;
            mi[r] = mnew;
#pragma unroll
            for (int hn = 0; hn < 8; ++hn) o[hn][r] *= alpha;
        }
        // ---- P: C-layout -> A-layout via per-wave LDS (in-order DS) ----
#pragma unroll
        for (int nt = 0; nt < 4; ++nt)
#pragma unroll
            for (int r = 0; r < 4; ++r)
                pl[wid][quad * 4 + r][nt * 16 + l16] = (__bf16)s[nt][r];
        asm volatile("s_waitcnt lgkmcnt(0)" ::: "memory");
        // ---- O += P V (V frags from LDS) ----
#pragma unroll
        for (int ks = 0; ks < 2; ++ks) {
            bf16x8 ap = *(const bf16x8*)&pl[wid][l16][ks * 32 + quad * 8];
#pragma unroll
            for (int hn = 0; hn < 8; ++hn) {
                bf16x8 vf = *(const bf16x8*)&Vs[hn * 16 + l16][ks * 32 + quad * 8];
                o[hn] = MFMA16(ap, vf, o[hn]);
            }
        }
    }

    // ---- epilogue: pre-normalized bf16 partial into out + (m,l) into ws ----
    __bf16* pb = (__bf16*)(out + (sb + r0) * 128) + half * 64 * 128;
#pragma unroll
    for (int r = 0; r < 4; ++r) {
        float inv = (li[r] > 0.f) ? 1.0f / li[r] : 0.f;
        int rt = wid * 16 + quad * 4 + r;              // row within tile
#pragma unroll
        for (int hn = 0; hn < 8; ++hn)
            pb[rt * 128 + hn * 16 + l16] = (__bf16)(o[hn][r] * inv);
        if (l16 == 0) {
            size_t mi_ = ((((size_t)(b * 64 + tile) * 2 + half) * 64) + rt) * 2;
            ml[mi_]     = mi[r];
            ml[mi_ + 1] = li[r];
        }
    }
}

// ------------------------------------------------------------ merge_halves --
// One block per (b,tile). Reads both bf16 partials from the out region + (m,l)
// from ws, barrier, writes final fp32 in place.
__global__ __launch_bounds__(256) void merge_halves(
    float* __restrict__ out, const float* __restrict__ ml)
{
    const int tile = blockIdx.x, b = blockIdx.y;
    const int r0 = tile * 64;
    const size_t sb = (size_t)b * 4096;
    const __bf16* pb = (const __bf16*)(out + (sb + r0) * 128);

    const int row = threadIdx.x >> 2, cb = (threadIdx.x & 3) * 32;
    size_t mi_ = (((size_t)(b * 64 + tile) * 2) * 64 + row) * 2;
    float m0 = ml[mi_],       l0 = ml[mi_ + 1];
    float m1 = ml[mi_ + 128], l1 = ml[mi_ + 129];
    float mm = fmaxf(m0, m1);
    float w0 = (l0 > 0.f) ? __expf(m0 - mm) * l0 : 0.f;
    float w1 = (l1 > 0.f) ? __expf(m1 - mm) * l1 : 0.f;
    float inv = 1.0f / (w0 + w1);
    w0 *= inv; w1 *= inv;

    bf16x8 a0[4], a1[4];
    const __bf16* p0 = pb + row * 128 + cb;
    const __bf16* p1 = pb + 64 * 128 + row * 128 + cb;
#pragma unroll
    for (int q = 0; q < 4; ++q) {
        a0[q] = *(const bf16x8*)&p0[q * 8];
        a1[q] = *(const bf16x8*)&p1[q * 8];
    }
    __syncthreads();                                   // all reads done
    float* op = &out[(sb + r0 + row) * 128 + cb];
#pragma unroll
    for (int q = 0; q < 4; ++q) {
        float4 r_;
        r_.x = w0 * (float)a0[q][0] + w1 * (float)a1[q][0];
        r_.y = w0 * (float)a0[q][1] + w1 * (float)a1[q][1];
        r_.z = w0 * (float)a0[q][2] + w1 * (float)a1[q][2];
        r_.w = w0 * (float)a0[q][3] + w1 * (float)a1[q][3];
        float4 r2;
        r2.x = w0 * (float)a0[q][4] + w1 * (float)a1[q][4];
        r2.y = w0 * (float)a0[q][5] + w1 * (float)a1[q][5];
        r2.z = w0 * (float)a0[q][6] + w1 * (float)a1[q][6];
        r2.w = w0 * (float)a0[q][7] + w1 * (float)a1[q][7];
        *(float4*)&op[q * 8]     = r_;
        *(float4*)&op[q * 8 + 4] = r2;
    }
}

// ----------------------------------------------------------------- launch ---
extern "C" void kernel_launch(void* const* d_in, const int* in_sizes, int n_in,
                              void* d_out, int out_size, void* d_ws, size_t ws_size,
                              hipStream_t stream)
{
    const float* x    = (const float*)d_in[0];
    const int*   mask = (const int*)d_in[1];
    const float* Wq   = (const float*)d_in[2];
    const float* bq   = (const float*)d_in[3];
    const float* Wk   = (const float*)d_in[4];
    const float* bk   = (const float*)d_in[5];
    const float* Wv   = (const float*)d_in[6];
    const float* bv   = (const float*)d_in[7];
    float* out = (float*)d_out;

    char* ws = (char*)d_ws;
    __bf16* Qb = (__bf16*)ws;                         // 4 MiB
    __bf16* Kb = Qb + (size_t)16384 * 128;            // 4 MiB
    __bf16* Vt = Kb + (size_t)16384 * 128;            // 4 MiB ([b][h][s])
    __bf16* Wb = Vt + (size_t)16384 * 128;            // 768 KiB
    float*  ml = (float*)(ws + 14155776);             // 256 KiB (m,l per row/half)

    prep_w<<<384, 256, 0, stream>>>(Wq, Wk, Wv, Wb);
    qkv_gemm<<<dim3(256, 3), 256, 0, stream>>>(x, Wb, bq, bk, bv, Qb, Kb, Vt);
    flash_attn<<<512, 256, 0, stream>>>(Qb, Kb, Vt, mask, out, ml);
    merge_halves<<<dim3(64, 4), 256, 0, stream>>>(out, ml);
}

// Round 7
// 273.534 us; speedup vs baseline: 1.3616x; 1.2229x over previous
//
#include <hip/hip_runtime.h>

// MaskedSelfAttention: B=4, S=4096, D=1024, H=128. fp32 in/out, bf16 MFMA compute.
// ws (~21.3 MiB): Qb bf16[16384][128] | Kb | Vt bf16[4][128][4096] | Wb bf16[384][1024]
//               | ml f32[4][32][4][128][2] | pex bf16[4][32][2][128][128]

typedef __bf16 bf16x8 __attribute__((ext_vector_type(8)));
typedef __bf16 bf16x4 __attribute__((ext_vector_type(4)));
typedef __bf16 bf16x2 __attribute__((ext_vector_type(2)));
typedef float  f32x4  __attribute__((ext_vector_type(4)));

#define MFMA16(a, b, c) __builtin_amdgcn_mfma_f32_16x16x32_bf16(a, b, c, 0, 0, 0)
#define EXP2F(x) __builtin_amdgcn_exp2f(x)

// ---------------------------------------------------------------- prep_w ----
__global__ __launch_bounds__(256) void prep_w(
    const float* __restrict__ Wq, const float* __restrict__ Wk,
    const float* __restrict__ Wv, __bf16* __restrict__ Wb)
{
    int i = (blockIdx.x * 256 + threadIdx.x) * 4;
    int row = i >> 10;
    const float* W = (row < 128) ? Wq : (row < 256) ? Wk : Wv;
    float4 v = *(const float4*)&W[(size_t)(row & 127) * 1024 + (i & 1023)];
    bf16x4 pk = {(__bf16)v.x, (__bf16)v.y, (__bf16)v.z, (__bf16)v.w};
    *(bf16x4*)&Wb[i] = pk;
}

// -------------------------------------------------------------- qkv_gemm ----
// v7: true LDS double-buffer, ONE barrier per K-iter. Block 64x128, 4 waves
// 2x2, wave 32x64 (2x4 MFMA 16x16x32), BK=64. Staging regs: 4 float4 (A,
// fp32->bf16 at store) + 4 uint4 (B). Loads for t+1 issue right after the
// barrier and are consumed a full compute phase later.
__global__ __launch_bounds__(256) void qkv_gemm(
    const float* __restrict__ x, const __bf16* __restrict__ Wb,
    const float* __restrict__ bq, const float* __restrict__ bk,
    const float* __restrict__ bv,
    __bf16* __restrict__ Qb, __bf16* __restrict__ Kb, __bf16* __restrict__ Vt)
{
    __shared__ __bf16 As[2][64][72];
    __shared__ __bf16 Bs[2][128][72];

    const int tid   = threadIdx.x;
    const int m0    = blockIdx.x * 64;
    const int which = blockIdx.y;           // 0=Q 1=K 2=V
    const int n0    = which * 128;
    const int lane = tid & 63, wid = tid >> 6;
    const int quad = lane >> 4, l16 = lane & 15;
    const int wm = (wid >> 1) * 32, wn = (wid & 1) * 64;

    const f32x4 fzero = {0.f, 0.f, 0.f, 0.f};
    f32x4 acc[2][4];
#pragma unroll
    for (int i = 0; i < 2; ++i)
#pragma unroll
        for (int j = 0; j < 4; ++j) acc[i][j] = fzero;

    const int arow = tid >> 2, ac = (tid & 3) * 16;   // A: 4 float4/thread
    const int brow = tid >> 1, bc = (tid & 1) * 32;   // B: 4 uint4/thread

    float4 ar[4];
    uint4  br[4];
    {
        const float* sa = &x[(size_t)(m0 + arow) * 1024 + ac];
#pragma unroll
        for (int q = 0; q < 4; ++q) ar[q] = *(const float4*)&sa[q * 4];
        const __bf16* sB = &Wb[(size_t)(n0 + brow) * 1024 + bc];
#pragma unroll
        for (int q = 0; q < 4; ++q) br[q] = *(const uint4*)&sB[q * 8];
    }

    for (int t = 0; t < 16; ++t) {
        const int buf = t & 1;
        {   // store staged regs (A: fp32 -> bf16)
            bf16x8 p0 = {(__bf16)ar[0].x, (__bf16)ar[0].y, (__bf16)ar[0].z, (__bf16)ar[0].w,
                         (__bf16)ar[1].x, (__bf16)ar[1].y, (__bf16)ar[1].z, (__bf16)ar[1].w};
            bf16x8 p1 = {(__bf16)ar[2].x, (__bf16)ar[2].y, (__bf16)ar[2].z, (__bf16)ar[2].w,
                         (__bf16)ar[3].x, (__bf16)ar[3].y, (__bf16)ar[3].z, (__bf16)ar[3].w};
            *(bf16x8*)&As[buf][arow][ac]     = p0;
            *(bf16x8*)&As[buf][arow][ac + 8] = p1;
#pragma unroll
            for (int q = 0; q < 4; ++q)
                *(uint4*)&Bs[buf][brow][bc + q * 8] = br[q];
        }
        __syncthreads();
        if (t < 15) {                       // prefetch t+1, consumed next iter
            const int kk = (t + 1) * 64;
            const float* sa = &x[(size_t)(m0 + arow) * 1024 + kk + ac];
#pragma unroll
            for (int q = 0; q < 4; ++q) ar[q] = *(const float4*)&sa[q * 4];
            const __bf16* sB = &Wb[(size_t)(n0 + brow) * 1024 + kk + bc];
#pragma unroll
            for (int q = 0; q < 4; ++q) br[q] = *(const uint4*)&sB[q * 8];
        }
#pragma unroll
        for (int ks = 0; ks < 2; ++ks) {
            const int k0 = ks * 32 + quad * 8;
            bf16x8 a[2], bb[4];
#pragma unroll
            for (int mt = 0; mt < 2; ++mt)
                a[mt] = *(const bf16x8*)&As[buf][wm + mt * 16 + l16][k0];
#pragma unroll
            for (int nt = 0; nt < 4; ++nt)
                bb[nt] = *(const bf16x8*)&Bs[buf][wn + nt * 16 + l16][k0];
#pragma unroll
            for (int mt = 0; mt < 2; ++mt)
#pragma unroll
                for (int nt = 0; nt < 4; ++nt)
                    acc[mt][nt] = MFMA16(a[mt], bb[nt], acc[mt][nt]);
        }
    }

    const float* bias = (which == 0) ? bq : (which == 1) ? bk : bv;
    if (which < 2) {
        __bf16* dst = (which == 0) ? Qb : Kb;
#pragma unroll
        for (int nt = 0; nt < 4; ++nt) {
            int col = wn + nt * 16 + l16;
            float bvv = bias[col];
#pragma unroll
            for (int mt = 0; mt < 2; ++mt)
#pragma unroll
                for (int r = 0; r < 4; ++r) {
                    int row = m0 + wm + mt * 16 + quad * 4 + r;
                    dst[(size_t)row * 128 + col] = (__bf16)(acc[mt][nt][r] + bvv);
                }
        }
    } else {
#pragma unroll
        for (int nt = 0; nt < 4; ++nt) {
            int col = wn + nt * 16 + l16;               // head index
            float bvv = bias[col];
#pragma unroll
            for (int mt = 0; mt < 2; ++mt) {
                int row = m0 + wm + mt * 16 + quad * 4;
                int bb_ = row >> 12, s = row & 4095;
                bf16x4 pk = {(__bf16)(acc[mt][nt][0] + bvv),
                             (__bf16)(acc[mt][nt][1] + bvv),
                             (__bf16)(acc[mt][nt][2] + bvv),
                             (__bf16)(acc[mt][nt][3] + bvv)};
                *(bf16x4*)&Vt[((size_t)(bb_ * 128 + col)) * 4096 + s] = pk;
            }
        }
    }
}

// -------------------------------------------------------------- flash_attn --
// v7: Q-tile 128 (4 waves x 32 q-cols), 64-key iters, quarter key-split ->
// 512 blocks (2/CU) with complementary big+small pairing. Computes S^T = K Q^T
// (A=K, B=Q) so softmax reduces over quads (2 shfls) and P packs to b32 LDS
// writes. O accumulates as O^T = V^T P^T; epilogue transposes via LDS and
// stores coalesced bf16 partials (2 in out, 2 in pex) + (m,l) in log2 domain.
__global__ __launch_bounds__(256, 2) void flash_attn(
    const __bf16* __restrict__ Qb, const __bf16* __restrict__ Kb,
    const __bf16* __restrict__ Vt, const int* __restrict__ mask,
    float* __restrict__ out, float* __restrict__ ml, __bf16* __restrict__ pex)
{
    __shared__ __align__(16) char smem[54272];
    __bf16 (*Ks)[136]     = (__bf16(*)[136])smem;              // [key64][d128]
    __bf16 (*Vs)[72]      = (__bf16(*)[72])(smem + 17408);     // [head128][key64]
    __bf16 (*plT)[32][72] = (__bf16(*)[32][72])(smem + 35840); // per-wave P^T
    __bf16 (*OL)[136]     = (__bf16(*)[136])smem;              // epilogue [q][head]

    const int idx  = blockIdx.x;
    const int rank = (idx < 256) ? idx : 767 - idx;    // pairs (c,c+256): big+small
    const int T  = 31 - (rank >> 4);
    const int b  = (rank >> 2) & 3;
    const int qr = rank & 3;
    const int r0 = T * 128;
    const int nk = 2 * (T + 1);
    const int chunk = (nk + 3) >> 2;
    const int t0 = qr * chunk;
    const int t1 = (nk < t0 + chunk) ? nk : t0 + chunk;

    const int tid = threadIdx.x, wid = tid >> 6, lane = tid & 63;
    const int quad = lane >> 4, l16 = lane & 15;
    const int qw = r0 + wid * 32;                      // wave's q base
    const size_t sb = (size_t)b * 4096;
    const float qs = 0.08838834764831845f * 1.4426950408889634f; // scale*log2e

    const int krow = tid >> 2, kcb = (tid & 3) * 32;   // K staging map
    const int vrow = tid >> 1, vcb = (tid & 1) * 32;   // V staging map

    bf16x8 qf[2][4];                                   // Q B-frags, scale folded
#pragma unroll
    for (int nf = 0; nf < 2; ++nf)
#pragma unroll
        for (int ks = 0; ks < 4; ++ks) {
            qf[nf][ks] = *(const bf16x8*)
                &Qb[(sb + qw + nf * 16 + l16) * 128 + ks * 32 + quad * 8];
#pragma unroll
            for (int j = 0; j < 8; ++j)
                qf[nf][ks][j] = (__bf16)((float)qf[nf][ks][j] * qs);
        }

    float mi[2] = {-1e30f, -1e30f}, li[2] = {0.f, 0.f};
    const f32x4 fzero = {0.f, 0.f, 0.f, 0.f};
    f32x4 o[8][2];                                     // O^T: 8 head-frags x 2 q-frags
#pragma unroll
    for (int hf = 0; hf < 8; ++hf)
#pragma unroll
        for (int nf = 0; nf < 2; ++nf) o[hf][nf] = fzero;

    uint4 kreg[4], vreg[4];
    if (t0 < t1) {
        const int k0 = t0 * 64;
#pragma unroll
        for (int i = 0; i < 4; ++i)
            kreg[i] = *(const uint4*)&Kb[(sb + k0 + krow) * 128 + kcb + i * 8];
#pragma unroll
        for (int i = 0; i < 4; ++i)
            vreg[i] = *(const uint4*)&Vt[(size_t)(b * 128 + vrow) * 4096 + k0 + vcb + i * 8];
    }

    for (int t = t0; t < t1; ++t) {
        const int k0 = t * 64;
        __syncthreads();
#pragma unroll
        for (int i = 0; i < 4; ++i) *(uint4*)&Ks[krow][kcb + i * 8] = kreg[i];
#pragma unroll
        for (int i = 0; i < 4; ++i) *(uint4*)&Vs[vrow][vcb + i * 8] = vreg[i];
        __syncthreads();
        if (t + 1 < t1) {
            const int kn = k0 + 64;
#pragma unroll
            for (int i = 0; i < 4; ++i)
                kreg[i] = *(const uint4*)&Kb[(sb + kn + krow) * 128 + kcb + i * 8];
#pragma unroll
            for (int i = 0; i < 4; ++i)
                vreg[i] = *(const uint4*)&Vt[(size_t)(b * 128 + vrow) * 4096 + kn + vcb + i * 8];
        }
        int mv = mask[sb + k0 + lane];

        // ---- S^T = K Q^T: rows=keys(64, 4 mf), cols=q(32, 2 nf) ----
        f32x4 s[4][2];
#pragma unroll
        for (int mf = 0; mf < 4; ++mf)
#pragma unroll
            for (int nf = 0; nf < 2; ++nf) s[mf][nf] = fzero;
#pragma unroll
        for (int ks = 0; ks < 4; ++ks)
#pragma unroll
            for (int mf = 0; mf < 4; ++mf) {
                bf16x8 a = *(const bf16x8*)&Ks[mf * 16 + l16][ks * 32 + quad * 8];
#pragma unroll
                for (int nf = 0; nf < 2; ++nf)
                    s[mf][nf] = MFMA16(a, qf[nf][ks], s[mf][nf]);
            }
        // ---- masking (C-layout: key = mf*16+quad*4+r, q = qw+nf*16+l16) ----
        unsigned long long mb = __ballot(mv != 0);
        if (mb != ~0ull || k0 + 63 > qw) {
#pragma unroll
            for (int mf = 0; mf < 4; ++mf)
#pragma unroll
                for (int r = 0; r < 4; ++r) {
                    int kl = mf * 16 + quad * 4 + r;
                    bool mok = (mb >> kl) & 1;
                    int kc = k0 + kl;
#pragma unroll
                    for (int nf = 0; nf < 2; ++nf) {
                        int q = qw + nf * 16 + l16;
                        bool ok = mok && (kc <= q);
                        s[mf][nf][r] = ok ? s[mf][nf][r] : -1e30f;
                    }
                }
        }
        // ---- online softmax per q (log2 domain; reduce over quads) ----
#pragma unroll
        for (int nf = 0; nf < 2; ++nf) {
            float mx = s[0][nf][0];
#pragma unroll
            for (int mf = 0; mf < 4; ++mf)
#pragma unroll
                for (int r = 0; r < 4; ++r) mx = fmaxf(mx, s[mf][nf][r]);
            mx = fmaxf(mx, __shfl_xor(mx, 16));
            mx = fmaxf(mx, __shfl_xor(mx, 32));
            float mnew  = fmaxf(mi[nf], mx);
            float alpha = EXP2F(mi[nf] - mnew);
            float rs = 0.f;
#pragma unroll
            for (int mf = 0; mf < 4; ++mf)
#pragma unroll
                for (int r = 0; r < 4; ++r) {
                    float sv = s[mf][nf][r];
                    float p = (sv < -5e29f) ? 0.f : EXP2F(sv - mnew);
                    s[mf][nf][r] = p;
                    rs += p;
                }
            rs += __shfl_xor(rs, 16);
            rs += __shfl_xor(rs, 32);
            li[nf] = li[nf] * alpha + rs;
            mi[nf] = mnew;
#pragma unroll
            for (int hf = 0; hf < 8; ++hf) {
                o[hf][nf][0] *= alpha; o[hf][nf][1] *= alpha;
                o[hf][nf][2] *= alpha; o[hf][nf][3] *= alpha;
            }
            // pack P (consecutive keys in-lane) -> b32 LDS writes
            int ql = nf * 16 + l16;
#pragma unroll
            for (int mf = 0; mf < 4; ++mf) {
                bf16x2 w0 = {(__bf16)s[mf][nf][0], (__bf16)s[mf][nf][1]};
                bf16x2 w1 = {(__bf16)s[mf][nf][2], (__bf16)s[mf][nf][3]};
                *(bf16x2*)&plT[wid][ql][mf * 16 + quad * 4]     = w0;
                *(bf16x2*)&plT[wid][ql][mf * 16 + quad * 4 + 2] = w1;
            }
        }
        asm volatile("s_waitcnt lgkmcnt(0)" ::: "memory"); // per-wave DS order
        // ---- O^T += V^T P^T ----
#pragma unroll
        for (int k2 = 0; k2 < 2; ++k2) {
            bf16x8 pb[2];
#pragma unroll
            for (int nf = 0; nf < 2; ++nf)
                pb[nf] = *(const bf16x8*)&plT[wid][nf * 16 + l16][k2 * 32 + quad * 8];
#pragma unroll
            for (int hf = 0; hf < 8; ++hf) {
                bf16x8 va = *(const bf16x8*)&Vs[hf * 16 + l16][k2 * 32 + quad * 8];
#pragma unroll
                for (int nf = 0; nf < 2; ++nf)
                    o[hf][nf] = MFMA16(va, pb[nf], o[hf][nf]);
            }
        }
    }

    // ---- epilogue: transpose O^T via LDS, coalesced bf16 partial store ----
    __syncthreads();                                   // main-loop LDS dead
    float inv[2];
#pragma unroll
    for (int nf = 0; nf < 2; ++nf) inv[nf] = (li[nf] > 0.f) ? 1.0f / li[nf] : 0.f;
#pragma unroll
    for (int nf = 0; nf < 2; ++nf) {
        int ql = wid * 32 + nf * 16 + l16;
#pragma unroll
        for (int hf = 0; hf < 8; ++hf) {
            int hd = hf * 16 + quad * 4;
            bf16x2 w0 = {(__bf16)(o[hf][nf][0] * inv[nf]), (__bf16)(o[hf][nf][1] * inv[nf])};
            bf16x2 w1 = {(__bf16)(o[hf][nf][2] * inv[nf]), (__bf16)(o[hf][nf][3] * inv[nf])};
            *(bf16x2*)&OL[ql][hd]     = w0;
            *(bf16x2*)&OL[ql][hd + 2] = w1;
        }
        if (quad == 0) {
            size_t base = (((size_t)(b * 32 + T) * 4 + qr) * 128 + ql) * 2;
            ml[base]     = mi[nf];
            ml[base + 1] = li[nf];
        }
    }
    __syncthreads();
    __bf16* dst = (qr < 2)
        ? (__bf16*)(out + (sb + r0) * 128) + (size_t)qr * 16384
        : pex + ((size_t)(b * 32 + T) * 2 + (qr - 2)) * 16384;
    {
        int qrow = tid >> 1, cb2 = (tid & 1) * 64;
#pragma unroll
        for (int i = 0; i < 8; ++i) {
            bf16x8 v = *(const bf16x8*)&OL[qrow][cb2 + i * 8];
            *(bf16x8*)&dst[(size_t)qrow * 128 + cb2 + i * 8] = v;
        }
    }
}

// ----------------------------------------------------------------- merge4 ---
// One block per (b,T): combine 4 pre-normalized bf16 quarter-partials
// (2 from out region, 2 from pex) into final fp32. Read-all -> barrier -> write.
__global__ __launch_bounds__(256) void merge4(
    float* __restrict__ out, const float* __restrict__ ml,
    const __bf16* __restrict__ pex)
{
    const int T = blockIdx.x, b = blockIdx.y;
    const int r0 = T * 128;
    const size_t sb = (size_t)b * 4096;
    const int ql = threadIdx.x >> 1, ch = (threadIdx.x & 1) * 64;

    float m[4], l[4];
#pragma unroll
    for (int qr = 0; qr < 4; ++qr) {
        size_t base = (((size_t)(b * 32 + T) * 4 + qr) * 128 + ql) * 2;
        m[qr] = ml[base];
        l[qr] = ml[base + 1];
    }
    float mm = fmaxf(fmaxf(m[0], m[1]), fmaxf(m[2], m[3]));
    float w[4], den = 0.f;
#pragma unroll
    for (int qr = 0; qr < 4; ++qr) {
        w[qr] = (l[qr] > 0.f) ? EXP2F(m[qr] - mm) * l[qr] : 0.f;
        den += w[qr];
    }
    float sc = (den > 0.f) ? 1.0f / den : 0.f;
#pragma unroll
    for (int qr = 0; qr < 4; ++qr) w[qr] *= sc;

    const __bf16* p0 = (const __bf16*)(out + (sb + r0) * 128);
    const __bf16* p[4] = {p0, p0 + 16384,
                          pex + ((size_t)(b * 32 + T) * 2) * 16384,
                          pex + ((size_t)(b * 32 + T) * 2 + 1) * 16384};
    bf16x8 rg[4][8];
#pragma unroll
    for (int qr = 0; qr < 4; ++qr)
#pragma unroll
        for (int i = 0; i < 8; ++i)
            rg[qr][i] = *(const bf16x8*)&p[qr][(size_t)ql * 128 + ch + i * 8];
    __syncthreads();                                   // all reads done
    float* op = &out[(sb + r0 + ql) * 128 + ch];
#pragma unroll
    for (int i = 0; i < 8; ++i) {
        float4 v0, v1;
        v0.x = w[0]*(float)rg[0][i][0] + w[1]*(float)rg[1][i][0] + w[2]*(float)rg[2][i][0] + w[3]*(float)rg[3][i][0];
        v0.y = w[0]*(float)rg[0][i][1] + w[1]*(float)rg[1][i][1] + w[2]*(float)rg[2][i][1] + w[3]*(float)rg[3][i][1];
        v0.z = w[0]*(float)rg[0][i][2] + w[1]*(float)rg[1][i][2] + w[2]*(float)rg[2][i][2] + w[3]*(float)rg[3][i][2];
        v0.w = w[0]*(float)rg[0][i][3] + w[1]*(float)rg[1][i][3] + w[2]*(float)rg[2][i][3] + w[3]*(float)rg[3][i][3];
        v1.x = w[0]*(float)rg[0][i][4] + w[1]*(float)rg[1][i][4] + w[2]*(float)rg[2][i][4] + w[3]*(float)rg[3][i][4];
        v1.y = w[0]*(float)rg[0][i][5] + w[1]*(float)rg[1][i][5] + w[2]*(float)rg[2][i][5] + w[3]*(float)rg[3][i][5];
        v1.z = w[0]*(float)rg[0][i][6] + w[1]*(float)rg[1][i][6] + w[2]*(float)rg[2][i][6] + w[3]*(float)rg[3][i][6];
        v1.w = w[0]*(float)rg[0][i][7] + w[1]*(float)rg[1][i][7] + w[2]*(float)rg[2][i][7] + w[3]*(float)rg[3][i][7];
        *(float4*)&op[i * 8]     = v0;
        *(float4*)&op[i * 8 + 4] = v1;
    }
}

// ----------------------------------------------------------------- launch ---
extern "C" void kernel_launch(void* const* d_in, const int* in_sizes, int n_in,
                              void* d_out, int out_size, void* d_ws, size_t ws_size,
                              hipStream_t stream)
{
    const float* x    = (const float*)d_in[0];
    const int*   mask = (const int*)d_in[1];
    const float* Wq   = (const float*)d_in[2];
    const float* bq   = (const float*)d_in[3];
    const float* Wk   = (const float*)d_in[4];
    const float* bk   = (const float*)d_in[5];
    const float* Wv   = (const float*)d_in[6];
    const float* bv   = (const float*)d_in[7];
    float* out = (float*)d_out;

    char* ws = (char*)d_ws;
    __bf16* Qb  = (__bf16*)ws;                        // 4 MiB
    __bf16* Kb  = Qb + (size_t)16384 * 128;           // 4 MiB
    __bf16* Vt  = Kb + (size_t)16384 * 128;           // 4 MiB ([b][h][s])
    __bf16* Wb  = Vt + (size_t)16384 * 128;           // 768 KiB @ 12,582,912
    float*  ml  = (float*)(ws + 13369344);            // 512 KiB
    __bf16* pex = (__bf16*)(ws + 13893632);           // 8 MiB (quarters 2,3)

    prep_w<<<384, 256, 0, stream>>>(Wq, Wk, Wv, Wb);
    qkv_gemm<<<dim3(256, 3), 256, 0, stream>>>(x, Wb, bq, bk, bv, Qb, Kb, Vt);
    flash_attn<<<512, 256, 0, stream>>>(Qb, Kb, Vt, mask, out, ml, pex);
    merge4<<<dim3(32, 4), 256, 0, stream>>>(out, ml, pex);
}